// Round 8
// baseline (670.186 us; speedup 1.0000x reference)
//
#include <hip/hip_runtime.h>

// LinearREncoder: concat(x,y) -> relu(W1)->relu(W2)->(aggregate)->W3 -> masked mean
// B=64 N=512 XD=YD=128 DIN=256 HD=4096 RD=1024. Lengths are PREFIX masks.
// R8..R12: compaction + packed-B + A-LDS dbuf; LDS conflicts -> 0 (978..788us).
// R13: layer-2 on i8 pipe (mfma_i32_16x16x64_i8, fused dequant): 632us.
// R14: i8 BK=128/phase (2-barrier): 607us, MODE1 317us.
// R15: 1-barrier + XCD swizzle: 679us. Swizzle broke B L2-residency (+620MB).
// R16: swizzle reverted, 1-barrier kept: 595us. CLEAN A/B: 1-barrier-2buf is
//      WORSE for MODE1 (341 vs 317: stage lead shrank to 1 phase < HBM
//      latency) but BETTER for short-K MODE0/2 (rest 290->254us).
// R17: MODE1 -> 3-deep LDS pipeline (bufs 0,1,2; 48KB; still 3 blk/CU):
//      2-phase stage lead AND 1 barrier/phase. vmcnt(12) = newer-than-stage(t)
//      {loadB(t-1)8 would already be drained, stage(t+1)4+loadB(t)8=12 kept}
//      -> stage(t+1) stays in flight across the barrier (T4 counted-vmcnt).
//      WAR: stage(t+2) targets buf[(t-1)%3]; its readers passed barrier_t.
//      MODE0/2 keep the R16 skeleton (measured faster for them).

using u16 = unsigned short;
using u8 = unsigned char;
typedef float f32x4 __attribute__((ext_vector_type(4)));
typedef short s16x8 __attribute__((ext_vector_type(8)));
typedef int i32x4 __attribute__((ext_vector_type(4)));

__device__ __forceinline__ u16 f2bf(float f) {
  union { float f; unsigned u; } v; v.f = f;
  unsigned r = (v.u + 0x7fffu + ((v.u >> 16) & 1u)) >> 16;  // RNE
  return (u16)r;
}

// ---------------- prep kernels ----------------

// lens[b] = sum of mask ints (bool arrives as int32 0/1)
__global__ void count_k(const int* __restrict__ mask, int* __restrict__ lens) {
  int b = blockIdx.x, l = threadIdx.x;  // 64 x 64
  const int4* row = (const int4*)(mask + (size_t)b * 512);
  int4 v0 = row[l];
  int4 v1 = row[l + 64];
  int s = v0.x + v0.y + v0.z + v0.w + v1.x + v1.y + v1.z + v1.w;
  #pragma unroll
  for (int o = 32; o; o >>= 1) s += __shfl_down(s, o);
  if (l == 0) lens[b] = s;
}

// meta[0..64] = prefix offsets, meta[65] = total, meta[66] = NT = ceil(total/128)
__global__ void meta_k(const int* __restrict__ lens, int* __restrict__ meta) {
  if (threadIdx.x == 0) {
    int acc = 0; meta[0] = 0;
    for (int b = 0; b < 64; ++b) { acc += lens[b]; meta[b + 1] = acc; }
    meta[65] = acc;
    meta[66] = (acc + 127) >> 7;
  }
}

// tok2b[i] = batch of compact token i (binary search), 64 for pad
__global__ void tok2b_k(const int* __restrict__ meta, int* __restrict__ tok2b) {
  int i = blockIdx.x * 256 + threadIdx.x;  // grid 128 -> 32768
  int total = meta[65];
  int b = 64;
  if (i < total) {
    int lo = 0, hi = 64;
    while (hi - lo > 1) { int mid = (lo + hi) >> 1; if (meta[mid] <= i) lo = mid; else hi = mid; }
    b = lo;
  }
  tok2b[i] = b;
}

// Compact A: A[m][0:128]=bf16(x[tok m]), A[m][128:256]=bf16(y[tok m]); pad rows 0
__global__ void build_a(const float* __restrict__ x, const float* __restrict__ y,
                        const int* __restrict__ meta, const int* __restrict__ tok2b,
                        u16* __restrict__ A) {
  int i4 = blockIdx.x * 256 + threadIdx.x;  // grid 8192
  int e = i4 * 4;
  int m = e >> 8, c = e & 255;
  int total = meta[65];
  ushort4 o = {0, 0, 0, 0};
  if (m < total) {
    int b = tok2b[m], t = m - meta[b];
    const float* src = (c < 128) ? x + ((size_t)b * 512 + t) * 128 + c
                                 : y + ((size_t)b * 512 + t) * 128 + (c - 128);
    float4 v = *(const float4*)src;
    o.x = f2bf(v.x); o.y = f2bf(v.y); o.z = f2bf(v.z); o.w = f2bf(v.w);
  }
  *(ushort4*)&A[e] = o;
}

// Pack W[K][N] f32 -> P in bf16 MFMA-fragment-tile order (W1, W3).
__global__ void pack_k(const float* __restrict__ W, u16* __restrict__ P,
                       int N, int NKB) {
  long c = (long)blockIdx.x * 256 + threadIdx.x;
  int lane = c & 63; long r = c >> 6;
  int s = r & 1; int j = (r >> 1) & 3; int wn = (r >> 3) & 1;
  long q = r >> 4;
  int ktb = (int)(q % NKB), nt = (int)(q / NKB);
  int k = ktb * 64 + s * 32 + (lane >> 4) * 8;
  int n = nt * 128 + wn * 64 + j * 16 + (lane & 15);
  ushort o[8];
  #pragma unroll
  for (int e = 0; e < 8; ++e) o[e] = f2bf(W[(size_t)(k + e) * N + n]);
  *(uint4*)&P[c * 8] = *(uint4*)o;
}

// cmax[n] = max_k |W2[k][n]|, via atomicMax on nonneg-float bit pattern.
__global__ void colmax_k(const float* __restrict__ W, float* __restrict__ cmax) {
  int n = blockIdx.x * 256 + threadIdx.x;        // grid (16, 32)
  int k0 = blockIdx.y * 128;
  float m = 0.f;
  for (int k = k0; k < k0 + 128; ++k)
    m = fmaxf(m, fabsf(W[(size_t)k * 4096 + n]));
  atomicMax((int*)&cmax[n], __float_as_int(m));  // valid: nonneg floats
}

// Pack W2[K=4096][N=4096] f32 -> i8 fragment-tile order for 16x16x64 MFMA.
// addr(nt,ktb,wn,j,lane,e) = ((nt*64+ktb)*8192) + wn*4096 + j*1024 + lane*16 + e
// with k = ktb*64 + (lane>>4)*16 + e, n = nt*128 + wn*64 + j*16 + (lane&15)
__global__ void pack8_k(const float* __restrict__ W, const float* __restrict__ cmax,
                        char* __restrict__ P) {
  long c = (long)blockIdx.x * 256 + threadIdx.x;  // grid 4096 -> 1M threads
  int lane = c & 63; long r = c >> 6;
  int j = r & 3; int wn = (r >> 2) & 1; long q = r >> 3;
  int ktb = (int)(q & 63), nt = (int)(q >> 6);
  int k = ktb * 64 + (lane >> 4) * 16;
  int n = nt * 128 + wn * 64 + j * 16 + (lane & 15);
  float rw = 127.0f / fmaxf(cmax[n], 1e-20f);
  char o[16];
  #pragma unroll
  for (int e = 0; e < 16; ++e) {
    int v = __float2int_rn(W[(size_t)(k + e) * 4096 + n] * rw);
    v = v > 127 ? 127 : (v < -127 ? -127 : v);
    o[e] = (char)v;
  }
  *(uint4*)&P[c * 16] = *(const uint4*)o;
}

// Sn[m][k] = bf16(S[m][k] / len[m]) for m<64, else 0
__global__ void sn_k(const float* __restrict__ S, const int* __restrict__ lens,
                     u16* __restrict__ Sn) {
  int i4 = blockIdx.x * 256 + threadIdx.x;  // grid 512
  int e = i4 * 4;
  int m = e >> 12;
  float inv = (m < 64) ? (1.0f / (float)lens[m]) : 0.0f;
  float4 v = *(const float4*)(S + e);
  ushort4 o;
  o.x = f2bf(v.x * inv); o.y = f2bf(v.y * inv);
  o.z = f2bf(v.z * inv); o.w = f2bf(v.w * inv);
  *(ushort4*)&Sn[e] = o;
}

// ---------------- main GEMM ----------------
// MODE 0: A bf16 (K=256, BK=64), Hout = i8(round(relu(acc+b)*32)) linear
// MODE 1: A i8 H1, B i8 W2, mfma_i32_16x16x64_i8, BK=128, 3-deep pipeline
// MODE 2: A bf16, Fout += acc (+bias on y=0), rows<64, split-K over blockIdx.y
template <int MODE>
__global__ __launch_bounds__(256, 3) void gemm_k(
    const void* __restrict__ Av, int lda, const void* __restrict__ BPv,
    const float* __restrict__ bias, const float* __restrict__ cmax,
    u8* __restrict__ Hout, float* __restrict__ Sout, float* __restrict__ Fout,
    const int* __restrict__ meta, const int* __restrict__ tok2b,
    int K, int Nld, int tile0, int tile_cap) {
  constexpr bool A8 = (MODE == 1);
  constexpr int BK = A8 ? 128 : 64;       // K per phase (one compute+barrier)
  __shared__ union {
    u16 a16[2][128 * 64];    // 32KB A dbuf (bf16 modes, BK=64)
    u8  a8[3][128 * 128];    // 48KB A 3-deep (i8 mode, BK=128)
    u8  outT8[128 * 128];    // MODE0 i8 repack (16KB)
  } sm;

  const int tid = threadIdx.x;
  const int wave = tid >> 6;
  const int lane = tid & 63;
  const int wm = wave >> 1, wn = wave & 1;
  const int quad = lane >> 4, l15 = lane & 15;
  const int NKB = K >> 6;

  int nslots;
  if constexpr (MODE < 2) {
    int tc = meta[66] - tile0;
    tc = tc < 0 ? 0 : (tc > tile_cap ? tile_cap : tc);
    nslots = tc * 32;
  } else {
    nslots = gridDim.x;
  }

  // Natural blockIdx order (R15 lesson): with mt-major slots and stride-768
  // grid-striding, XCD x only ever touches n0-blocks {(x+8j) mod 32} = 4
  // distinct -> its 2MB of B stays L2-resident. Do NOT XCD-swizzle here.
  for (int slot = blockIdx.x; slot < nslots; slot += gridDim.x) {
    int mt, n0, k0, kend;
    if constexpr (MODE < 2) {
      mt = slot >> 5; n0 = (slot & 31) << 7; k0 = 0; kend = K;
    } else {
      mt = 0; n0 = slot << 7; k0 = blockIdx.y * 512; kend = k0 + 512;
    }

    f32x4 accf[4][4];
    i32x4 acci[4][4];
    #pragma unroll
    for (int i = 0; i < 4; i++)
      #pragma unroll
      for (int j = 0; j < 4; j++) {
        if constexpr (A8) acci[i][j] = (i32x4){0, 0, 0, 0};
        else accf[i][j] = (f32x4){0.f, 0.f, 0.f, 0.f};
      }

    // A staging: proven 1024-chunk pattern per buffer: chunk ci -> row
    // m = ci>>3, LDS slot c_lds = ci&7 holds global 16B chunk c = (ci&7)^(m&7).
    // Read side: c_lds = c_read ^ (m&7) -> 0 conflicts (R8..R16 measured).
    const u8* ag8[4];
    const u16* ag16[4];
    if constexpr (A8) {
      #pragma unroll
      for (int il = 0; il < 4; ++il) {
        int ci = (wave * 4 + il) * 64 + lane;   // 1024 chunks x 16B = 16KB
        int m = ci >> 3, c = (ci & 7) ^ (m & 7);
        ag8[il] = (const u8*)Av + (size_t)(mt * 128 + m) * lda + c * 16;
      }
    } else {
      #pragma unroll
      for (int il = 0; il < 4; ++il) {
        int ci = (wave * 4 + il) * 64 + lane;
        int m = ci >> 3, c = (ci & 7) ^ (m & 7);
        ag16[il] = (const u16*)Av + (size_t)(mt * 128 + m) * lda + c * 8;
      }
    }
    const u16* bw = nullptr;
    const u8* bw8 = nullptr;
    if constexpr (A8)
      bw8 = (const u8*)BPv + (size_t)(n0 >> 7) * NKB * 8192 + wn * 4096 + lane * 16;
    else
      bw = (const u16*)BPv + (size_t)(n0 >> 7) * NKB * 8192 + wn * 4096 + lane * 8;

    s16x8 breg0[8], breg1[8];
    i32x4 breg8_0[8], breg8_1[8];

    auto stageA = [&](int kt, int buf) {
      if constexpr (A8) {
        #pragma unroll
        for (int il = 0; il < 4; ++il)
          __builtin_amdgcn_global_load_lds(
              (const __attribute__((address_space(1))) void*)(ag8[il] + kt),
              (__attribute__((address_space(3))) void*)(&sm.a8[buf][(wave * 4 + il) * 1024]),
              16, 0, 0);
      } else {
        #pragma unroll
        for (int il = 0; il < 4; ++il)
          __builtin_amdgcn_global_load_lds(
              (const __attribute__((address_space(1))) void*)(ag16[il] + kt),
              (__attribute__((address_space(3))) void*)(&sm.a16[buf][(wave * 4 + il) * 512]),
              16, 0, 0);
      }
    };
    auto loadB = [&](int kt, int which) {
      if constexpr (A8) {
        // BK=128: two K-64 fragment blocks (s=0,1), 4 n-frags each = 8 x b128
        i32x4* dst = which ? breg8_1 : breg8_0;
        const u8* p = bw8 + (size_t)(kt >> 6) * 8192;
        #pragma unroll
        for (int s = 0; s < 2; s++)
          #pragma unroll
          for (int j = 0; j < 4; j++)
            dst[s * 4 + j] = *(const i32x4*)(p + s * 8192 + j * 1024);
      } else {
        s16x8* dst = which ? breg1 : breg0;
        const u16* p = bw + (size_t)(kt >> 6) * 8192;
        #pragma unroll
        for (int j = 0; j < 4; j++)
          #pragma unroll
          for (int s = 0; s < 2; s++)
            dst[j * 2 + s] = *(const s16x8*)(p + j * 1024 + s * 512);
      }
    };
    auto compute = [&](int buf, int which) {
      if constexpr (A8) {
        const i32x4* br = which ? breg8_1 : breg8_0;
        const u8* ab = &sm.a8[0][0] + buf * 16384;  // runtime buf: LDS addr only
        #pragma unroll
        for (int s = 0; s < 2; ++s) {
          #pragma unroll
          for (int i = 0; i < 4; i++) {
            int m = wm * 64 + i * 16 + l15;
            int c = (s * 4 + quad) ^ (m & 7);
            i32x4 a = *(const i32x4*)&ab[(m * 8 + c) * 16];
            #pragma unroll
            for (int j = 0; j < 4; j++)
              acci[i][j] = __builtin_amdgcn_mfma_i32_16x16x64_i8(
                  a, br[s * 4 + j], acci[i][j], 0, 0, 0);
          }
        }
      } else {
        const s16x8* br = which ? breg1 : breg0;
        #pragma unroll
        for (int s = 0; s < 2; ++s) {
          s16x8 af[4];
          #pragma unroll
          for (int i = 0; i < 4; i++) {
            int m = wm * 64 + i * 16 + l15;
            int c = (s * 4 + quad) ^ (m & 7);
            af[i] = *(const s16x8*)&sm.a16[buf][(m * 8 + c) * 8];
          }
          #pragma unroll
          for (int i = 0; i < 4; i++)
            #pragma unroll
            for (int j = 0; j < 4; j++)
              accf[i][j] = __builtin_amdgcn_mfma_f32_16x16x32_bf16(
                  af[i], br[j * 2 + s], accf[i][j], 0, 0, 0);
        }
      }
    };

    if constexpr (A8) {
      // 3-deep, 1 barrier/phase. Per phase t:
      //   vmcnt(12); barrier; stage(t+2 -> buf[(t+2)%3]); SB0; loadB(t+1);
      //   compute(buf[t%3])
      // vmcnt(12): FIFO queue at wait = [stage(t)4, loadB(t-1)8, stage(t+1)4,
      // loadB(t)8]; compute(t-1)'s implicit wait already retired the first 12;
      // explicit 12 keeps stage(t+1)+loadB(t) IN FLIGHT across the barrier
      // (2-phase stage lead). WAR: buf[(t+2)%3] == buf[(t-1)%3]; its readers
      // (compute t-1) all passed barrier_t with LDS reads complete.
      stageA(k0, 0);
      stageA(k0 + BK, 1);
      loadB(k0, 0);
      const int NP = (kend - k0) / BK;  // 32, even
      int bufc = 0, bufs = 2;
      for (int t = 0; t < NP; t += 2) {
        int kt = k0 + t * BK;
        // ---- phase t (breg0) ----
        __builtin_amdgcn_s_waitcnt(0x0F7C);  // vmcnt(12)
        __builtin_amdgcn_s_barrier();
        if (t + 2 < NP) stageA(kt + 2 * BK, bufs);
        __builtin_amdgcn_sched_barrier(0);   // pin stage before loadB (FIFO)
        loadB(kt + BK, 1);
        compute(bufc, 0);
        bufc = bufc == 2 ? 0 : bufc + 1;
        bufs = bufs == 2 ? 0 : bufs + 1;
        // ---- phase t+1 (breg1) ----
        __builtin_amdgcn_s_waitcnt(0x0F7C);  // vmcnt(12)
        __builtin_amdgcn_s_barrier();
        if (t + 3 < NP) stageA(kt + 3 * BK, bufs);
        __builtin_amdgcn_sched_barrier(0);
        if (t + 2 < NP) loadB(kt + 2 * BK, 0);
        compute(bufc, 1);
        bufc = bufc == 2 ? 0 : bufc + 1;
        bufs = bufs == 2 ? 0 : bufs + 1;
      }
    } else {
      // R16 1-barrier 2-buf skeleton (measured faster for short-K modes).
      stageA(k0, 0);
      loadB(k0, 0);
      const int NP = (kend - k0) / BK;  // even
      for (int t = 0; t < NP; t += 2) {
        int kt = k0 + t * BK;
        __builtin_amdgcn_s_waitcnt(0x0F78);  // vmcnt(8)
        __builtin_amdgcn_s_barrier();
        stageA(kt + BK, 1);
        __builtin_amdgcn_sched_barrier(0);
        loadB(kt + BK, 1);
        compute(0, 0);
        __builtin_amdgcn_s_waitcnt(0x0F78);  // vmcnt(8)
        __builtin_amdgcn_s_barrier();
        if (t + 2 < NP) {
          stageA(kt + 2 * BK, 0);
          __builtin_amdgcn_sched_barrier(0);
          loadB(kt + 2 * BK, 0);
        }
        compute(1, 1);
      }
    }
    __syncthreads();

    // epilogues (C/D layout: col = lane&15, row = quad*4 + reg; dtype-indep)
    if constexpr (MODE == 0) {
      float bb[4];
      #pragma unroll
      for (int j = 0; j < 4; j++) bb[j] = bias[n0 + wn * 64 + j * 16 + l15];
      #pragma unroll
      for (int i = 0; i < 4; i++)
        #pragma unroll
        for (int j = 0; j < 4; j++) {
          int col = wn * 64 + j * 16 + l15;
          #pragma unroll
          for (int r = 0; r < 4; r++) {
            int row = wm * 64 + i * 16 + quad * 4 + r;
            float v = accf[i][j][r] + bb[j];
            v = v > 0.f ? v : 0.f;
            int qv = (int)(v * 32.0f + 0.5f);   // h1 quant, scale 32
            if (qv > 127) qv = 127;
            sm.outT8[row * 128 + col] = (u8)qv;
          }
        }
      __syncthreads();
      #pragma unroll
      for (int u = 0; u < 4; ++u) {   // linear emit
        int e = u * 256 + tid;
        int row = e >> 3, c16 = (e & 7) * 16;
        *(uint4*)&Hout[(size_t)(mt * 128 + row) * Nld + n0 + c16] =
            *(const uint4*)&sm.outT8[row * 128 + c16];
      }
      __syncthreads();
    } else if constexpr (MODE == 1) {
      float bb[4], sc[4];
      #pragma unroll
      for (int j = 0; j < 4; j++) {
        int col_ = n0 + wn * 64 + j * 16 + l15;
        bb[j] = bias[col_];
        sc[j] = cmax[col_] * (1.0f / (127.0f * 32.0f));  // dequant scale
      }
      int tb[16];
      const int gbase = tile0 * 128 + mt * 128 + wm * 64 + quad * 4;
      #pragma unroll
      for (int i = 0; i < 4; i++)
        #pragma unroll
        for (int r = 0; r < 4; r++) tb[i * 4 + r] = tok2b[gbase + i * 16 + r];
      #pragma unroll
      for (int j = 0; j < 4; j++) {
        int col = n0 + wn * 64 + j * 16 + l15;
        float sum = 0.f;
        int cb = tb[0];
        #pragma unroll
        for (int idx = 0; idx < 16; ++idx) {
          float t = (float)acci[idx >> 2][j][idx & 3] * sc[j] + bb[j];
          t = t > 0.f ? t : 0.f;
          int b = tb[idx];
          if (b != cb) {
            atomicAdd(&Sout[(size_t)cb * 4096 + col], sum);
            sum = 0.f; cb = b;
          }
          sum += t;
        }
        atomicAdd(&Sout[(size_t)cb * 4096 + col], sum);
      }
    } else {
      float bb[4];
      #pragma unroll
      for (int j = 0; j < 4; j++)
        bb[j] = (blockIdx.y == 0) ? bias[n0 + wn * 64 + j * 16 + l15] : 0.f;
      #pragma unroll
      for (int i = 0; i < 4; i++)
        #pragma unroll
        for (int j = 0; j < 4; j++) {
          int col = wn * 64 + j * 16 + l15;
          #pragma unroll
          for (int r = 0; r < 4; r++) {
            int row = wm * 64 + i * 16 + quad * 4 + r;
            if (row < 64)
              atomicAdd(&Fout[(size_t)row * Nld + n0 + col], accf[i][j][r] + bb[j]);
          }
        }
    }
  }
}

// ---------------- host ----------------
extern "C" void kernel_launch(void* const* d_in, const int* in_sizes, int n_in,
                              void* d_out, int out_size, void* d_ws, size_t ws_size,
                              hipStream_t stream) {
  const float* x  = (const float*)d_in[0];
  const float* y  = (const float*)d_in[1];
  const int* mask = (const int*)d_in[2];
  const float* W1 = (const float*)d_in[3];
  const float* b1 = (const float*)d_in[4];
  const float* W2 = (const float*)d_in[5];
  const float* b2 = (const float*)d_in[6];
  const float* W3 = (const float*)d_in[7];
  const float* b3 = (const float*)d_in[8];
  float* out = (float*)d_out;

  char* ws = (char*)d_ws;
  size_t off = 0;
  auto alloc = [&](size_t bytes) {
    char* p = ws + off;
    off += (bytes + 255) & ~(size_t)255;
    return p;
  };
  int* lens  = (int*)alloc(64 * 4);
  int* meta  = (int*)alloc(70 * 4);
  int* tok2b = (int*)alloc((size_t)32768 * 4);
  float* S   = (float*)alloc((size_t)128 * 4096 * 4);
  u16* Sn    = (u16*)alloc((size_t)128 * 4096 * 2);
  float* cm  = (float*)alloc((size_t)4096 * 4);
  u16* W1P   = (u16*)alloc((size_t)256 * 4096 * 2);
  char* W2P8 = (char*)alloc((size_t)4096 * 4096);
  u16* W3P   = (u16*)alloc((size_t)4096 * 1024 * 2);
  u16* Abuf  = (u16*)alloc((size_t)32768 * 256 * 2);
  size_t fixed = off;
  size_t h1_full = (size_t)32768 * 4096;  // 134MB i8 (256 tiles)
  int nchunks, tile_cap;
  if (ws_size >= fixed + h1_full) { nchunks = 1; tile_cap = 256; }
  else if (ws_size >= fixed + h1_full / 2) { nchunks = 2; tile_cap = 128; }
  else if (ws_size >= fixed + h1_full / 4) { nchunks = 4; tile_cap = 64; }
  else return;
  u8* H1 = (u8*)alloc(h1_full / nchunks);

  hipMemsetAsync(S, 0, (size_t)128 * 4096 * 4, stream);
  hipMemsetAsync(cm, 0, (size_t)4096 * 4, stream);
  hipMemsetAsync(out, 0, (size_t)out_size * 4, stream);
  count_k<<<64, 64, 0, stream>>>(mask, lens);
  meta_k<<<1, 64, 0, stream>>>(lens, meta);
  tok2b_k<<<128, 256, 0, stream>>>(meta, tok2b);
  build_a<<<8192, 256, 0, stream>>>(x, y, meta, tok2b, Abuf);
  pack_k<<<512, 256, 0, stream>>>(W1, W1P, 4096, 4);    // K=256
  colmax_k<<<dim3(16, 32), 256, 0, stream>>>(W2, cm);
  pack8_k<<<4096, 256, 0, stream>>>(W2, cm, W2P8);      // i8, K=4096
  pack_k<<<2048, 256, 0, stream>>>(W3, W3P, 1024, 64);  // K=4096

  for (int c = 0; c < nchunks; ++c) {
    gemm_k<0><<<dim3(768), 256, 0, stream>>>(
        Abuf + (size_t)c * tile_cap * 128 * 256, 256, W1P, b1, nullptr, H1,
        nullptr, nullptr, meta, tok2b, 256, 4096, c * tile_cap, tile_cap);
    gemm_k<1><<<dim3(768), 256, 0, stream>>>(
        H1, 4096, W2P8, b2, cm, nullptr, S, nullptr,
        meta, tok2b, 4096, 4096, c * tile_cap, tile_cap);
  }
  sn_k<<<512, 256, 0, stream>>>(S, lens, Sn);
  gemm_k<2><<<dim3(8, 8), 256, 0, stream>>>(
      Sn, 4096, W3P, b3, nullptr, nullptr, nullptr, out,
      meta, tok2b, 4096, 1024, 0, 0);
}

// Round 9
// 576.653 us; speedup vs baseline: 1.1622x; 1.1622x over previous
//
#include <hip/hip_runtime.h>

// LinearREncoder: concat(x,y) -> relu(W1)->relu(W2)->(aggregate)->W3 -> masked mean
// B=64 N=512 XD=YD=128 DIN=256 HD=4096 RD=1024. Lengths are PREFIX masks.
// R8..R12: compaction + packed-B + A-LDS dbuf; LDS conflicts -> 0 (978..788us).
// R13: layer-2 on i8 pipe (mfma_i32_16x16x64_i8, fused dequant): 632us.
// R14: i8 BK=128/phase, 2-barrier KSTEP=256 skeleton: 607us, MODE1 317us.
// R15: 1-barrier + XCD swizzle: 679 (swizzle broke B L2-residency, +620MB).
// R16: swizzle reverted, 1-barrier everywhere: 595us. MODE1 341 (worse than
//      R14's 317: stage lead shrank), but MODE0/2 rest 290->254us (better).
// R17: 3-deep pipeline for MODE1: 670us (MODE1 409). FIFO in-order vmcnt
//      retirement put loadB(t) behind stage(t+1) -> MFMA data path gated on a
//      fresh HBM stage. MfmaUtil 36->29. Lesson: never queue fast B-loads
//      behind slow A-stages within the window a compute will wait on.
// R18: composition of measured bests, no new structure:
//      MODE1  = R14 2-barrier KSTEP=256 skeleton (317us measured)
//      MODE0/2 = R16 1-barrier 2-buf skeleton   (rest 254us measured)
//      LDS back to 32KB union; natural block order (B L2-resident per XCD).

using u16 = unsigned short;
using u8 = unsigned char;
typedef float f32x4 __attribute__((ext_vector_type(4)));
typedef short s16x8 __attribute__((ext_vector_type(8)));
typedef int i32x4 __attribute__((ext_vector_type(4)));

__device__ __forceinline__ u16 f2bf(float f) {
  union { float f; unsigned u; } v; v.f = f;
  unsigned r = (v.u + 0x7fffu + ((v.u >> 16) & 1u)) >> 16;  // RNE
  return (u16)r;
}

// ---------------- prep kernels ----------------

// lens[b] = sum of mask ints (bool arrives as int32 0/1)
__global__ void count_k(const int* __restrict__ mask, int* __restrict__ lens) {
  int b = blockIdx.x, l = threadIdx.x;  // 64 x 64
  const int4* row = (const int4*)(mask + (size_t)b * 512);
  int4 v0 = row[l];
  int4 v1 = row[l + 64];
  int s = v0.x + v0.y + v0.z + v0.w + v1.x + v1.y + v1.z + v1.w;
  #pragma unroll
  for (int o = 32; o; o >>= 1) s += __shfl_down(s, o);
  if (l == 0) lens[b] = s;
}

// meta[0..64] = prefix offsets, meta[65] = total, meta[66] = NT = ceil(total/128)
__global__ void meta_k(const int* __restrict__ lens, int* __restrict__ meta) {
  if (threadIdx.x == 0) {
    int acc = 0; meta[0] = 0;
    for (int b = 0; b < 64; ++b) { acc += lens[b]; meta[b + 1] = acc; }
    meta[65] = acc;
    meta[66] = (acc + 127) >> 7;
  }
}

// tok2b[i] = batch of compact token i (binary search), 64 for pad
__global__ void tok2b_k(const int* __restrict__ meta, int* __restrict__ tok2b) {
  int i = blockIdx.x * 256 + threadIdx.x;  // grid 128 -> 32768
  int total = meta[65];
  int b = 64;
  if (i < total) {
    int lo = 0, hi = 64;
    while (hi - lo > 1) { int mid = (lo + hi) >> 1; if (meta[mid] <= i) lo = mid; else hi = mid; }
    b = lo;
  }
  tok2b[i] = b;
}

// Compact A: A[m][0:128]=bf16(x[tok m]), A[m][128:256]=bf16(y[tok m]); pad rows 0
__global__ void build_a(const float* __restrict__ x, const float* __restrict__ y,
                        const int* __restrict__ meta, const int* __restrict__ tok2b,
                        u16* __restrict__ A) {
  int i4 = blockIdx.x * 256 + threadIdx.x;  // grid 8192
  int e = i4 * 4;
  int m = e >> 8, c = e & 255;
  int total = meta[65];
  ushort4 o = {0, 0, 0, 0};
  if (m < total) {
    int b = tok2b[m], t = m - meta[b];
    const float* src = (c < 128) ? x + ((size_t)b * 512 + t) * 128 + c
                                 : y + ((size_t)b * 512 + t) * 128 + (c - 128);
    float4 v = *(const float4*)src;
    o.x = f2bf(v.x); o.y = f2bf(v.y); o.z = f2bf(v.z); o.w = f2bf(v.w);
  }
  *(ushort4*)&A[e] = o;
}

// Pack W[K][N] f32 -> P in bf16 MFMA-fragment-tile order (W1, W3).
__global__ void pack_k(const float* __restrict__ W, u16* __restrict__ P,
                       int N, int NKB) {
  long c = (long)blockIdx.x * 256 + threadIdx.x;
  int lane = c & 63; long r = c >> 6;
  int s = r & 1; int j = (r >> 1) & 3; int wn = (r >> 3) & 1;
  long q = r >> 4;
  int ktb = (int)(q % NKB), nt = (int)(q / NKB);
  int k = ktb * 64 + s * 32 + (lane >> 4) * 8;
  int n = nt * 128 + wn * 64 + j * 16 + (lane & 15);
  ushort o[8];
  #pragma unroll
  for (int e = 0; e < 8; ++e) o[e] = f2bf(W[(size_t)(k + e) * N + n]);
  *(uint4*)&P[c * 8] = *(uint4*)o;
}

// cmax[n] = max_k |W2[k][n]|, via atomicMax on nonneg-float bit pattern.
__global__ void colmax_k(const float* __restrict__ W, float* __restrict__ cmax) {
  int n = blockIdx.x * 256 + threadIdx.x;        // grid (16, 32)
  int k0 = blockIdx.y * 128;
  float m = 0.f;
  for (int k = k0; k < k0 + 128; ++k)
    m = fmaxf(m, fabsf(W[(size_t)k * 4096 + n]));
  atomicMax((int*)&cmax[n], __float_as_int(m));  // valid: nonneg floats
}

// Pack W2[K=4096][N=4096] f32 -> i8 fragment-tile order for 16x16x64 MFMA.
// addr(nt,ktb,wn,j,lane,e) = ((nt*64+ktb)*8192) + wn*4096 + j*1024 + lane*16 + e
// with k = ktb*64 + (lane>>4)*16 + e, n = nt*128 + wn*64 + j*16 + (lane&15)
__global__ void pack8_k(const float* __restrict__ W, const float* __restrict__ cmax,
                        char* __restrict__ P) {
  long c = (long)blockIdx.x * 256 + threadIdx.x;  // grid 4096 -> 1M threads
  int lane = c & 63; long r = c >> 6;
  int j = r & 3; int wn = (r >> 2) & 1; long q = r >> 3;
  int ktb = (int)(q & 63), nt = (int)(q >> 6);
  int k = ktb * 64 + (lane >> 4) * 16;
  int n = nt * 128 + wn * 64 + j * 16 + (lane & 15);
  float rw = 127.0f / fmaxf(cmax[n], 1e-20f);
  char o[16];
  #pragma unroll
  for (int e = 0; e < 16; ++e) {
    int v = __float2int_rn(W[(size_t)(k + e) * 4096 + n] * rw);
    v = v > 127 ? 127 : (v < -127 ? -127 : v);
    o[e] = (char)v;
  }
  *(uint4*)&P[c * 16] = *(const uint4*)o;
}

// Sn[m][k] = bf16(S[m][k] / len[m]) for m<64, else 0
__global__ void sn_k(const float* __restrict__ S, const int* __restrict__ lens,
                     u16* __restrict__ Sn) {
  int i4 = blockIdx.x * 256 + threadIdx.x;  // grid 512
  int e = i4 * 4;
  int m = e >> 12;
  float inv = (m < 64) ? (1.0f / (float)lens[m]) : 0.0f;
  float4 v = *(const float4*)(S + e);
  ushort4 o;
  o.x = f2bf(v.x * inv); o.y = f2bf(v.y * inv);
  o.z = f2bf(v.z * inv); o.w = f2bf(v.w * inv);
  *(ushort4*)&Sn[e] = o;
}

// ---------------- main GEMM ----------------
// MODE 0: A bf16 (K=256, BK=64), Hout = i8(round(relu(acc+b)*32)) linear
// MODE 1: A i8 H1, B i8 W2, mfma_i32_16x16x64_i8, BK=128, R14 2-barrier
// MODE 2: A bf16, Fout += acc (+bias on y=0), rows<64, split-K over blockIdx.y
template <int MODE>
__global__ __launch_bounds__(256, 3) void gemm_k(
    const void* __restrict__ Av, int lda, const void* __restrict__ BPv,
    const float* __restrict__ bias, const float* __restrict__ cmax,
    u8* __restrict__ Hout, float* __restrict__ Sout, float* __restrict__ Fout,
    const int* __restrict__ meta, const int* __restrict__ tok2b,
    int K, int Nld, int tile0, int tile_cap) {
  constexpr bool A8 = (MODE == 1);
  constexpr int BK = A8 ? 128 : 64;       // K per compute phase
  __shared__ union {
    u16 a16[2][128 * 64];   // 32KB A dbuf (bf16 modes, BK=64)
    u8  a8[2][128 * 128];   // 32KB A dbuf (i8 mode, BK=128)
    u8  outT8[128 * 128];   // MODE0 i8 repack (16KB)
  } sm;

  const int tid = threadIdx.x;
  const int wave = tid >> 6;
  const int lane = tid & 63;
  const int wm = wave >> 1, wn = wave & 1;
  const int quad = lane >> 4, l15 = lane & 15;
  const int NKB = K >> 6;

  int nslots;
  if constexpr (MODE < 2) {
    int tc = meta[66] - tile0;
    tc = tc < 0 ? 0 : (tc > tile_cap ? tile_cap : tc);
    nslots = tc * 32;
  } else {
    nslots = gridDim.x;
  }

  // Natural blockIdx order (R15 lesson): with mt-major slots and stride-768
  // grid-striding, XCD x only ever touches n0-blocks {(x+8j) mod 32} = 4
  // distinct -> its 2MB of B stays L2-resident. Do NOT XCD-swizzle here.
  for (int slot = blockIdx.x; slot < nslots; slot += gridDim.x) {
    int mt, n0, k0, kend;
    if constexpr (MODE < 2) {
      mt = slot >> 5; n0 = (slot & 31) << 7; k0 = 0; kend = K;
    } else {
      mt = 0; n0 = slot << 7; k0 = blockIdx.y * 512; kend = k0 + 512;
    }

    f32x4 accf[4][4];
    i32x4 acci[4][4];
    #pragma unroll
    for (int i = 0; i < 4; i++)
      #pragma unroll
      for (int j = 0; j < 4; j++) {
        if constexpr (A8) acci[i][j] = (i32x4){0, 0, 0, 0};
        else accf[i][j] = (f32x4){0.f, 0.f, 0.f, 0.f};
      }

    // A staging: proven 1024-chunk pattern per buffer: chunk ci -> row
    // m = ci>>3, LDS slot c_lds = ci&7 holds global 16B chunk c = (ci&7)^(m&7).
    // Read side: c_lds = c_read ^ (m&7) -> 0 conflicts (R8..R17 measured).
    const u8* ag8[4];
    const u16* ag16[4];
    if constexpr (A8) {
      #pragma unroll
      for (int il = 0; il < 4; ++il) {
        int ci = (wave * 4 + il) * 64 + lane;   // 1024 chunks x 16B = 16KB
        int m = ci >> 3, c = (ci & 7) ^ (m & 7);
        ag8[il] = (const u8*)Av + (size_t)(mt * 128 + m) * lda + c * 16;
      }
    } else {
      #pragma unroll
      for (int il = 0; il < 4; ++il) {
        int ci = (wave * 4 + il) * 64 + lane;
        int m = ci >> 3, c = (ci & 7) ^ (m & 7);
        ag16[il] = (const u16*)Av + (size_t)(mt * 128 + m) * lda + c * 8;
      }
    }
    const u16* bw = nullptr;
    const u8* bw8 = nullptr;
    if constexpr (A8)
      bw8 = (const u8*)BPv + (size_t)(n0 >> 7) * NKB * 8192 + wn * 4096 + lane * 16;
    else
      bw = (const u16*)BPv + (size_t)(n0 >> 7) * NKB * 8192 + wn * 4096 + lane * 8;

    s16x8 breg0[8], breg1[8];
    i32x4 breg8_0[8], breg8_1[8];

    auto stageA = [&](int kt, int buf) {
      if constexpr (A8) {
        #pragma unroll
        for (int il = 0; il < 4; ++il)
          __builtin_amdgcn_global_load_lds(
              (const __attribute__((address_space(1))) void*)(ag8[il] + kt),
              (__attribute__((address_space(3))) void*)(&sm.a8[buf][(wave * 4 + il) * 1024]),
              16, 0, 0);
      } else {
        #pragma unroll
        for (int il = 0; il < 4; ++il)
          __builtin_amdgcn_global_load_lds(
              (const __attribute__((address_space(1))) void*)(ag16[il] + kt),
              (__attribute__((address_space(3))) void*)(&sm.a16[buf][(wave * 4 + il) * 512]),
              16, 0, 0);
      }
    };
    auto loadB = [&](int kt, int which) {
      if constexpr (A8) {
        // BK=128: two K-64 fragment blocks (s=0,1), 4 n-frags each = 8 x b128
        i32x4* dst = which ? breg8_1 : breg8_0;
        const u8* p = bw8 + (size_t)(kt >> 6) * 8192;
        #pragma unroll
        for (int s = 0; s < 2; s++)
          #pragma unroll
          for (int j = 0; j < 4; j++)
            dst[s * 4 + j] = *(const i32x4*)(p + s * 8192 + j * 1024);
      } else {
        s16x8* dst = which ? breg1 : breg0;
        const u16* p = bw + (size_t)(kt >> 6) * 8192;
        #pragma unroll
        for (int j = 0; j < 4; j++)
          #pragma unroll
          for (int s = 0; s < 2; s++)
            dst[j * 2 + s] = *(const s16x8*)(p + j * 1024 + s * 512);
      }
    };
    auto compute = [&](int buf, int which) {
      if constexpr (A8) {
        const i32x4* br = which ? breg8_1 : breg8_0;
        #pragma unroll
        for (int s = 0; s < 2; ++s) {
          #pragma unroll
          for (int i = 0; i < 4; i++) {
            int m = wm * 64 + i * 16 + l15;
            int c = (s * 4 + quad) ^ (m & 7);
            i32x4 a = *(const i32x4*)&sm.a8[buf][(m * 8 + c) * 16];
            #pragma unroll
            for (int j = 0; j < 4; j++)
              acci[i][j] = __builtin_amdgcn_mfma_i32_16x16x64_i8(
                  a, br[s * 4 + j], acci[i][j], 0, 0, 0);
          }
        }
      } else {
        const s16x8* br = which ? breg1 : breg0;
        #pragma unroll
        for (int s = 0; s < 2; ++s) {
          s16x8 af[4];
          #pragma unroll
          for (int i = 0; i < 4; i++) {
            int m = wm * 64 + i * 16 + l15;
            int c = (s * 4 + quad) ^ (m & 7);
            af[i] = *(const s16x8*)&sm.a16[buf][(m * 8 + c) * 8];
          }
          #pragma unroll
          for (int i = 0; i < 4; i++)
            #pragma unroll
            for (int j = 0; j < 4; j++)
              accf[i][j] = __builtin_amdgcn_mfma_f32_16x16x32_bf16(
                  af[i], br[j * 2 + s], accf[i][j], 0, 0, 0);
        }
      }
    };

    if constexpr (A8) {
      // R14 2-barrier KSTEP=256 skeleton (measured best for long-K: 317us).
      // vmcnt(12) drains {stage(cur)4, loadB(cur)8} together; stage lead
      // ~1.5 phases; B-loads never queue behind a stage the compute waits on.
      constexpr int KSTEP = 2 * BK;
      stageA(k0, 0);
      if (k0 + BK < kend) stageA(k0 + BK, 1);
      loadB(k0, 0);
      for (int kt = k0; kt < kend; kt += KSTEP) {
        loadB(kt + BK, 1);
        __builtin_amdgcn_s_waitcnt(0x0F7C);  // vmcnt(12)
        __builtin_amdgcn_s_barrier();
        compute(0, 0);
        __builtin_amdgcn_s_barrier();
        if (kt + KSTEP < kend) stageA(kt + KSTEP, 0);
        if (kt + KSTEP < kend) {
          loadB(kt + KSTEP, 0);
          __builtin_amdgcn_s_waitcnt(0x0F7C);  // vmcnt(12)
        } else {
          __builtin_amdgcn_s_waitcnt(0x0F70);  // vmcnt(0): last iter
        }
        __builtin_amdgcn_s_barrier();
        compute(1, 1);
        __builtin_amdgcn_s_barrier();
        if (kt + KSTEP + BK < kend) stageA(kt + KSTEP + BK, 1);
      }
    } else {
      // R16 1-barrier 2-buf skeleton (measured best for short-K modes).
      stageA(k0, 0);
      loadB(k0, 0);
      const int NP = (kend - k0) / BK;  // even
      for (int t = 0; t < NP; t += 2) {
        int kt = k0 + t * BK;
        __builtin_amdgcn_s_waitcnt(0x0F78);  // vmcnt(8)
        __builtin_amdgcn_s_barrier();
        stageA(kt + BK, 1);
        __builtin_amdgcn_sched_barrier(0);
        loadB(kt + BK, 1);
        compute(0, 0);
        __builtin_amdgcn_s_waitcnt(0x0F78);  // vmcnt(8)
        __builtin_amdgcn_s_barrier();
        if (t + 2 < NP) {
          stageA(kt + 2 * BK, 0);
          __builtin_amdgcn_sched_barrier(0);
          loadB(kt + 2 * BK, 0);
        }
        compute(1, 1);
      }
    }
    __syncthreads();

    // epilogues (C/D layout: col = lane&15, row = quad*4 + reg; dtype-indep)
    if constexpr (MODE == 0) {
      float bb[4];
      #pragma unroll
      for (int j = 0; j < 4; j++) bb[j] = bias[n0 + wn * 64 + j * 16 + l15];
      #pragma unroll
      for (int i = 0; i < 4; i++)
        #pragma unroll
        for (int j = 0; j < 4; j++) {
          int col = wn * 64 + j * 16 + l15;
          #pragma unroll
          for (int r = 0; r < 4; r++) {
            int row = wm * 64 + i * 16 + quad * 4 + r;
            float v = accf[i][j][r] + bb[j];
            v = v > 0.f ? v : 0.f;
            int qv = (int)(v * 32.0f + 0.5f);   // h1 quant, scale 32
            if (qv > 127) qv = 127;
            sm.outT8[row * 128 + col] = (u8)qv;
          }
        }
      __syncthreads();
      #pragma unroll
      for (int u = 0; u < 4; ++u) {   // linear emit
        int e = u * 256 + tid;
        int row = e >> 3, c16 = (e & 7) * 16;
        *(uint4*)&Hout[(size_t)(mt * 128 + row) * Nld + n0 + c16] =
            *(const uint4*)&sm.outT8[row * 128 + c16];
      }
      __syncthreads();
    } else if constexpr (MODE == 1) {
      float bb[4], sc[4];
      #pragma unroll
      for (int j = 0; j < 4; j++) {
        int col_ = n0 + wn * 64 + j * 16 + l15;
        bb[j] = bias[col_];
        sc[j] = cmax[col_] * (1.0f / (127.0f * 32.0f));  // dequant scale
      }
      int tb[16];
      const int gbase = tile0 * 128 + mt * 128 + wm * 64 + quad * 4;
      #pragma unroll
      for (int i = 0; i < 4; i++)
        #pragma unroll
        for (int r = 0; r < 4; r++) tb[i * 4 + r] = tok2b[gbase + i * 16 + r];
      #pragma unroll
      for (int j = 0; j < 4; j++) {
        int col = n0 + wn * 64 + j * 16 + l15;
        float sum = 0.f;
        int cb = tb[0];
        #pragma unroll
        for (int idx = 0; idx < 16; ++idx) {
          float t = (float)acci[idx >> 2][j][idx & 3] * sc[j] + bb[j];
          t = t > 0.f ? t : 0.f;
          int b = tb[idx];
          if (b != cb) {
            atomicAdd(&Sout[(size_t)cb * 4096 + col], sum);
            sum = 0.f; cb = b;
          }
          sum += t;
        }
        atomicAdd(&Sout[(size_t)cb * 4096 + col], sum);
      }
    } else {
      float bb[4];
      #pragma unroll
      for (int j = 0; j < 4; j++)
        bb[j] = (blockIdx.y == 0) ? bias[n0 + wn * 64 + j * 16 + l15] : 0.f;
      #pragma unroll
      for (int i = 0; i < 4; i++)
        #pragma unroll
        for (int j = 0; j < 4; j++) {
          int col = wn * 64 + j * 16 + l15;
          #pragma unroll
          for (int r = 0; r < 4; r++) {
            int row = wm * 64 + i * 16 + quad * 4 + r;
            if (row < 64)
              atomicAdd(&Fout[(size_t)row * Nld + n0 + col], accf[i][j][r] + bb[j]);
          }
        }
    }
  }
}

// ---------------- host ----------------
extern "C" void kernel_launch(void* const* d_in, const int* in_sizes, int n_in,
                              void* d_out, int out_size, void* d_ws, size_t ws_size,
                              hipStream_t stream) {
  const float* x  = (const float*)d_in[0];
  const float* y  = (const float*)d_in[1];
  const int* mask = (const int*)d_in[2];
  const float* W1 = (const float*)d_in[3];
  const float* b1 = (const float*)d_in[4];
  const float* W2 = (const float*)d_in[5];
  const float* b2 = (const float*)d_in[6];
  const float* W3 = (const float*)d_in[7];
  const float* b3 = (const float*)d_in[8];
  float* out = (float*)d_out;

  char* ws = (char*)d_ws;
  size_t off = 0;
  auto alloc = [&](size_t bytes) {
    char* p = ws + off;
    off += (bytes + 255) & ~(size_t)255;
    return p;
  };
  int* lens  = (int*)alloc(64 * 4);
  int* meta  = (int*)alloc(70 * 4);
  int* tok2b = (int*)alloc((size_t)32768 * 4);
  float* S   = (float*)alloc((size_t)128 * 4096 * 4);
  u16* Sn    = (u16*)alloc((size_t)128 * 4096 * 2);
  float* cm  = (float*)alloc((size_t)4096 * 4);
  u16* W1P   = (u16*)alloc((size_t)256 * 4096 * 2);
  char* W2P8 = (char*)alloc((size_t)4096 * 4096);
  u16* W3P   = (u16*)alloc((size_t)4096 * 1024 * 2);
  u16* Abuf  = (u16*)alloc((size_t)32768 * 256 * 2);
  size_t fixed = off;
  size_t h1_full = (size_t)32768 * 4096;  // 134MB i8 (256 tiles)
  int nchunks, tile_cap;
  if (ws_size >= fixed + h1_full) { nchunks = 1; tile_cap = 256; }
  else if (ws_size >= fixed + h1_full / 2) { nchunks = 2; tile_cap = 128; }
  else if (ws_size >= fixed + h1_full / 4) { nchunks = 4; tile_cap = 64; }
  else return;
  u8* H1 = (u8*)alloc(h1_full / nchunks);

  hipMemsetAsync(S, 0, (size_t)128 * 4096 * 4, stream);
  hipMemsetAsync(cm, 0, (size_t)4096 * 4, stream);
  hipMemsetAsync(out, 0, (size_t)out_size * 4, stream);
  count_k<<<64, 64, 0, stream>>>(mask, lens);
  meta_k<<<1, 64, 0, stream>>>(lens, meta);
  tok2b_k<<<128, 256, 0, stream>>>(meta, tok2b);
  build_a<<<8192, 256, 0, stream>>>(x, y, meta, tok2b, Abuf);
  pack_k<<<512, 256, 0, stream>>>(W1, W1P, 4096, 4);    // K=256
  colmax_k<<<dim3(16, 32), 256, 0, stream>>>(W2, cm);
  pack8_k<<<4096, 256, 0, stream>>>(W2, cm, W2P8);      // i8, K=4096
  pack_k<<<2048, 256, 0, stream>>>(W3, W3P, 1024, 64);  // K=4096

  for (int c = 0; c < nchunks; ++c) {
    gemm_k<0><<<dim3(768), 256, 0, stream>>>(
        Abuf + (size_t)c * tile_cap * 128 * 256, 256, W1P, b1, nullptr, H1,
        nullptr, nullptr, meta, tok2b, 256, 4096, c * tile_cap, tile_cap);
    gemm_k<1><<<dim3(768), 256, 0, stream>>>(
        H1, 4096, W2P8, b2, cm, nullptr, S, nullptr,
        meta, tok2b, 4096, 4096, c * tile_cap, tile_cap);
  }
  sn_k<<<512, 256, 0, stream>>>(S, lens, Sn);
  gemm_k<2><<<dim3(8, 8), 256, 0, stream>>>(
      Sn, 4096, W3P, b3, nullptr, nullptr, nullptr, out,
      meta, tok2b, 4096, 1024, 0, 0);
}